// Round 1
// baseline (838.351 us; speedup 1.0000x reference)
//
#include <hip/hip_runtime.h>
#include <hip/hip_bf16.h>

// GAT: 3x (GATConv + Linear skip), N=50000, E=800000(+N self loops)
// IN=128, HID=32, H=4, H_LAST=6, OUT=2, NEG=0.2
// Strategy: device-built CSR by dst (no fp atomics), wave-per-node aggregation,
// LDS-tiled fp32 GEMM computing conv-XW and linear skip in one launch.

#define NEG_SLOPE 0.2f

static __device__ __forceinline__ float leaky(float x) {
    return x > 0.f ? x : NEG_SLOPE * x;
}

// ---------------- CSR build ----------------

__global__ void k_hist(const int* ei, int E, int N, int* cnt) {
    int e = blockIdx.x * blockDim.x + threadIdx.x;
    if (e >= E + N) return;
    int d = (e < E) ? ei[E + e] : (e - E);
    atomicAdd(&cnt[d], 1);
}

__global__ void k_scan1(const int* cnt, int* incl, int* bsum, int N) {
    __shared__ int sm[256];
    int tid = threadIdx.x;
    int i = blockIdx.x * 256 + tid;
    int v = (i < N) ? cnt[i] : 0;
    sm[tid] = v;
    __syncthreads();
    for (int off = 1; off < 256; off <<= 1) {
        int t = (tid >= off) ? sm[tid - off] : 0;
        __syncthreads();
        sm[tid] += t;
        __syncthreads();
    }
    if (i < N) incl[i] = sm[tid];
    if (tid == 255) bsum[blockIdx.x] = sm[255];
}

__global__ void k_scan2(int* bsum, int nb) {
    __shared__ int sm[1024];
    int tid = threadIdx.x;
    int v = (tid < nb) ? bsum[tid] : 0;
    sm[tid] = v;
    __syncthreads();
    for (int off = 1; off < 1024; off <<= 1) {
        int t = (tid >= off) ? sm[tid - off] : 0;
        __syncthreads();
        sm[tid] += t;
        __syncthreads();
    }
    if (tid < nb) bsum[tid] = sm[tid] - v;  // exclusive block offsets
}

__global__ void k_scan3(int* rowptr, const int* cnt, const int* bsum, int N) {
    int i = blockIdx.x * 256 + threadIdx.x;
    if (i >= N) return;
    int incl = rowptr[i];
    int c = cnt[i];
    int excl = incl - c + bsum[blockIdx.x];
    rowptr[i] = excl;
    if (i == N - 1) rowptr[N] = excl + c;
}

__global__ void k_scatter(const int* ei, int E, int N, const int* rowptr, int* cnt, int* col) {
    int e = blockIdx.x * blockDim.x + threadIdx.x;
    if (e >= E + N) return;
    int s, d;
    if (e < E) { s = ei[e]; d = ei[E + e]; }
    else       { s = e - E; d = e - E; }
    int pos = rowptr[d] + atomicAdd(&cnt[d], 1);
    col[pos] = s;
}

// ---------------- GEMM: C1 = A@B1 (no bias), C2 = A@B2 + b2 ----------------
// A: [M,128] row-major. B1,B2: [128,128] row-major. grid.y in [0,4):
//   y>>1 selects B1/B2, y&1 selects 64-col half.
__global__ __launch_bounds__(256) void k_gemm_dual(
    const float* __restrict__ A,
    const float* __restrict__ B1, float* __restrict__ C1,
    const float* __restrict__ B2, const float* __restrict__ b2, float* __restrict__ C2,
    int M) {
    __shared__ float As[32][65];
    __shared__ float Bs[32][65];
    int which = blockIdx.y >> 1;
    const float* B = which ? B2 : B1;
    float* C = which ? C2 : C1;
    const float* bias = which ? b2 : nullptr;
    int row0 = blockIdx.x * 64;
    int col0 = (blockIdx.y & 1) * 64;
    int tid = threadIdx.x;
    int tx = tid & 15, ty = tid >> 4;

    float acc[4][4];
#pragma unroll
    for (int i = 0; i < 4; i++)
#pragma unroll
        for (int j = 0; j < 4; j++) acc[i][j] = 0.f;

    for (int k0 = 0; k0 < 128; k0 += 32) {
#pragma unroll
        for (int i = 0; i < 8; i++) {
            int e = tid + i * 256;
            int m = e >> 5, k = e & 31;
            int gr = row0 + m;
            As[k][m] = (gr < M) ? A[gr * 128 + k0 + k] : 0.f;
        }
#pragma unroll
        for (int i = 0; i < 8; i++) {
            int e = tid + i * 256;
            int k = e >> 6, n = e & 63;
            Bs[k][n] = B[(k0 + k) * 128 + col0 + n];
        }
        __syncthreads();
#pragma unroll
        for (int kk = 0; kk < 32; kk++) {
            float a[4], b[4];
#pragma unroll
            for (int i = 0; i < 4; i++) a[i] = As[kk][ty * 4 + i];
#pragma unroll
            for (int j = 0; j < 4; j++) b[j] = Bs[kk][tx * 4 + j];
#pragma unroll
            for (int i = 0; i < 4; i++)
#pragma unroll
                for (int j = 0; j < 4; j++) acc[i][j] += a[i] * b[j];
        }
        __syncthreads();
    }
#pragma unroll
    for (int i = 0; i < 4; i++) {
        int gr = row0 + ty * 4 + i;
        if (gr >= M) continue;
#pragma unroll
        for (int j = 0; j < 4; j++) {
            int gc = col0 + tx * 4 + j;
            float v = acc[i][j];
            if (bias) v += bias[gc];
            C[gr * 128 + gc] = v;
        }
    }
}

// ---------------- attention logits per node/head (H=4, C=32) ----------------
__global__ void k_alsald(const float* __restrict__ XW,
                         const float* __restrict__ a_s, const float* __restrict__ a_d,
                         float* __restrict__ ALS, float* __restrict__ ALD, int N) {
    int t = blockIdx.x * blockDim.x + threadIdx.x;
    if (t >= N * 4) return;
    int n = t >> 2, h = t & 3;
    const float* xr = XW + n * 128 + h * 32;
    const float* as = a_s + h * 32;
    const float* ad = a_d + h * 32;
    float s = 0.f, d = 0.f;
#pragma unroll
    for (int c = 0; c < 32; c++) {
        float v = xr[c];
        s += v * as[c];
        d += v * ad[c];
    }
    ALS[n * 4 + h] = s;
    ALD[n * 4 + h] = d;
}

// ---------------- aggregation for H=4, C=32, concat, + skip + relu ----------
// H (in/out): contains LIN (skip) on entry; replaced with final layer output.
__global__ __launch_bounds__(256) void k_agg4(
    const int* __restrict__ rowptr, const int* __restrict__ col,
    const float* __restrict__ XW, const float* __restrict__ ALS,
    const float* __restrict__ ALD, const float* __restrict__ cb,
    float* __restrict__ H, int N) {
    int wid = threadIdx.x >> 6, lane = threadIdx.x & 63;
    int node = blockIdx.x * 4 + wid;
    if (node >= N) return;
    int start = rowptr[node], end = rowptr[node + 1];

    float ald[4], mx[4], sm[4];
#pragma unroll
    for (int h = 0; h < 4; h++) { ald[h] = ALD[node * 4 + h]; mx[h] = -1e30f; sm[h] = 0.f; }

    for (int i = start + lane; i < end; i += 64) {
        int s = col[i];
#pragma unroll
        for (int h = 0; h < 4; h++) {
            float a = leaky(ALS[s * 4 + h] + ald[h]);
            mx[h] = fmaxf(mx[h], a);
        }
    }
#pragma unroll
    for (int m = 32; m >= 1; m >>= 1)
#pragma unroll
        for (int h = 0; h < 4; h++) mx[h] = fmaxf(mx[h], __shfl_xor(mx[h], m));

    for (int i = start + lane; i < end; i += 64) {
        int s = col[i];
#pragma unroll
        for (int h = 0; h < 4; h++) {
            float a = leaky(ALS[s * 4 + h] + ald[h]);
            sm[h] += __expf(a - mx[h]);
        }
    }
#pragma unroll
    for (int m = 32; m >= 1; m >>= 1)
#pragma unroll
        for (int h = 0; h < 4; h++) sm[h] += __shfl_xor(sm[h], m);

    // pass 3: lanes own channels. oc1=lane (heads 0/1), oc2=lane+64 (heads 2/3)
    int hi = (lane & 32) ? 1 : 0;
    float aldA = hi ? ald[1] : ald[0];
    float aldB = hi ? ald[3] : ald[2];
    float mxA = hi ? mx[1] : mx[0];
    float mxB = hi ? mx[3] : mx[2];
    float invA = 1.f / (hi ? sm[1] : sm[0]);
    float invB = 1.f / (hi ? sm[3] : sm[2]);
    int hA = hi, hB = hi + 2;
    float accA = 0.f, accB = 0.f;
    for (int i = start; i < end; i++) {
        int s = col[i];
        float a = leaky(ALS[s * 4 + hA] + aldA);
        float cA = __expf(a - mxA) * invA;
        float b = leaky(ALS[s * 4 + hB] + aldB);
        float cB = __expf(b - mxB) * invB;
        const float* xr = XW + s * 128;
        accA += xr[lane] * cA;
        accB += xr[lane + 64] * cB;
    }
    int oc1 = lane, oc2 = lane + 64;
    float o1 = accA + cb[oc1] + H[node * 128 + oc1];
    float o2 = accB + cb[oc2] + H[node * 128 + oc2];
    H[node * 128 + oc1] = o1 > 0.f ? o1 : 0.f;
    H[node * 128 + oc2] = o2 > 0.f ? o2 : 0.f;
}

// ---------------- layer 2 prep: XW2[N,12], ALS2/ALD2[N,6], lin2 -> out ------
__global__ __launch_bounds__(256) void k_l2prep(
    const float* __restrict__ H1, const float* __restrict__ c2W,
    const float* __restrict__ c2as, const float* __restrict__ c2ad,
    const float* __restrict__ l2W, const float* __restrict__ l2b,
    float* __restrict__ XW2, float* __restrict__ ALS2, float* __restrict__ ALD2,
    float* __restrict__ out, int N) {
    int wid = threadIdx.x >> 6, lane = threadIdx.x & 63;
    int node = blockIdx.x * 4 + wid;
    if (node >= N) return;
    float h1 = H1[node * 128 + lane];
    float h2 = H1[node * 128 + 64 + lane];
    float p[14];
#pragma unroll
    for (int j = 0; j < 12; j++)
        p[j] = h1 * c2W[lane * 12 + j] + h2 * c2W[(lane + 64) * 12 + j];
    p[12] = h1 * l2W[lane * 2 + 0] + h2 * l2W[(lane + 64) * 2 + 0];
    p[13] = h1 * l2W[lane * 2 + 1] + h2 * l2W[(lane + 64) * 2 + 1];
#pragma unroll
    for (int m = 32; m >= 1; m >>= 1)
#pragma unroll
        for (int j = 0; j < 14; j++) p[j] += __shfl_xor(p[j], m);
    if (lane == 0) {
#pragma unroll
        for (int h = 0; h < 6; h++) {
            float a = p[h * 2] * c2as[h * 2] + p[h * 2 + 1] * c2as[h * 2 + 1];
            float d = p[h * 2] * c2ad[h * 2] + p[h * 2 + 1] * c2ad[h * 2 + 1];
            ALS2[node * 6 + h] = a;
            ALD2[node * 6 + h] = d;
        }
#pragma unroll
        for (int j = 0; j < 12; j++) XW2[node * 12 + j] = p[j];
        out[node * 2 + 0] = p[12] + l2b[0];
        out[node * 2 + 1] = p[13] + l2b[1];
    }
}

// ---------------- aggregation for H_LAST=6, C=2, mean, + c2_b ---------------
__global__ __launch_bounds__(256) void k_agg2(
    const int* __restrict__ rowptr, const int* __restrict__ col,
    const float* __restrict__ XW2, const float* __restrict__ ALS2,
    const float* __restrict__ ALD2, const float* __restrict__ c2b,
    float* __restrict__ out, int N) {
    int wid = threadIdx.x >> 6, lane = threadIdx.x & 63;
    int node = blockIdx.x * 4 + wid;
    if (node >= N) return;
    int start = rowptr[node], end = rowptr[node + 1];

    float ald[6], mx[6], sm[6];
#pragma unroll
    for (int h = 0; h < 6; h++) { ald[h] = ALD2[node * 6 + h]; mx[h] = -1e30f; sm[h] = 0.f; }

    for (int i = start + lane; i < end; i += 64) {
        int s = col[i];
#pragma unroll
        for (int h = 0; h < 6; h++) {
            float a = leaky(ALS2[s * 6 + h] + ald[h]);
            mx[h] = fmaxf(mx[h], a);
        }
    }
#pragma unroll
    for (int m = 32; m >= 1; m >>= 1)
#pragma unroll
        for (int h = 0; h < 6; h++) mx[h] = fmaxf(mx[h], __shfl_xor(mx[h], m));

    for (int i = start + lane; i < end; i += 64) {
        int s = col[i];
#pragma unroll
        for (int h = 0; h < 6; h++) {
            float a = leaky(ALS2[s * 6 + h] + ald[h]);
            sm[h] += __expf(a - mx[h]);
        }
    }
#pragma unroll
    for (int m = 32; m >= 1; m >>= 1)
#pragma unroll
        for (int h = 0; h < 6; h++) sm[h] += __shfl_xor(sm[h], m);

    float acc = 0.f;
    if (lane < 12) {
        int h = lane >> 1;
        float aldh = (h == 0) ? ald[0] : (h == 1) ? ald[1] : (h == 2) ? ald[2]
                   : (h == 3) ? ald[3] : (h == 4) ? ald[4] : ald[5];
        float mxh = (h == 0) ? mx[0] : (h == 1) ? mx[1] : (h == 2) ? mx[2]
                  : (h == 3) ? mx[3] : (h == 4) ? mx[4] : mx[5];
        float smh = (h == 0) ? sm[0] : (h == 1) ? sm[1] : (h == 2) ? sm[2]
                  : (h == 3) ? sm[3] : (h == 4) ? sm[4] : sm[5];
        float invh = 1.f / smh;
        for (int i = start; i < end; i++) {
            int s = col[i];
            float a = leaky(ALS2[s * 6 + h] + aldh);
            float c = __expf(a - mxh) * invh;
            acc += XW2[s * 12 + lane] * c;
        }
    }
    // sum heads of same output channel: lanes {c, c+2, ..., c+10} (+ zero lanes 12..15)
    acc += __shfl_xor(acc, 2);
    acc += __shfl_xor(acc, 4);
    acc += __shfl_xor(acc, 8);
    if (lane < 2)
        out[node * 2 + lane] += acc * (1.f / 6.f) + c2b[lane];
}

// ---------------- launch ----------------

extern "C" void kernel_launch(void* const* d_in, const int* in_sizes, int n_in,
                              void* d_out, int out_size, void* d_ws, size_t ws_size,
                              hipStream_t stream) {
    const float* x   = (const float*)d_in[0];
    const int* ei    = (const int*)d_in[1];
    // d_in[2] edge_attr: ignored
    const float* c0W = (const float*)d_in[3];
    const float* c0as = (const float*)d_in[4];
    const float* c0ad = (const float*)d_in[5];
    const float* c0b = (const float*)d_in[6];
    const float* l0W = (const float*)d_in[7];
    const float* l0b = (const float*)d_in[8];
    const float* c1W = (const float*)d_in[9];
    const float* c1as = (const float*)d_in[10];
    const float* c1ad = (const float*)d_in[11];
    const float* c1b = (const float*)d_in[12];
    const float* l1W = (const float*)d_in[13];
    const float* l1b = (const float*)d_in[14];
    const float* c2W = (const float*)d_in[15];
    const float* c2as = (const float*)d_in[16];
    const float* c2ad = (const float*)d_in[17];
    const float* c2b = (const float*)d_in[18];
    const float* l2W = (const float*)d_in[19];
    const float* l2b = (const float*)d_in[20];
    float* out = (float*)d_out;

    const int N = in_sizes[0] / 128;
    const int E = in_sizes[1] / 2;
    const int ET = E + N;

    // workspace carve (256B aligned)
    char* p = (char*)d_ws;
    auto alloc = [&](size_t bytes) -> void* {
        void* r = (void*)p;
        p += (bytes + 255) & ~(size_t)255;
        return r;
    };
    float* H0  = (float*)alloc((size_t)N * 128 * 4);
    float* H1  = (float*)alloc((size_t)N * 128 * 4);
    float* XW  = (float*)alloc((size_t)N * 128 * 4);
    float* ALS = (float*)alloc((size_t)N * 6 * 4);
    float* ALD = (float*)alloc((size_t)N * 6 * 4);
    int* rowptr = (int*)alloc((size_t)(N + 1) * 4);
    int* cnt    = (int*)alloc((size_t)N * 4);
    int* bsum   = (int*)alloc(4096);
    int* col    = (int*)alloc((size_t)ET * 4);

    const int nb = (N + 255) / 256;

    // --- CSR build ---
    hipMemsetAsync(cnt, 0, (size_t)N * 4, stream);
    k_hist<<<(ET + 255) / 256, 256, 0, stream>>>(ei, E, N, cnt);
    k_scan1<<<nb, 256, 0, stream>>>(cnt, rowptr, bsum, N);
    k_scan2<<<1, 1024, 0, stream>>>(bsum, nb);
    k_scan3<<<nb, 256, 0, stream>>>(rowptr, cnt, bsum, N);
    hipMemsetAsync(cnt, 0, (size_t)N * 4, stream);
    k_scatter<<<(ET + 255) / 256, 256, 0, stream>>>(ei, E, N, rowptr, cnt, col);

    dim3 ggrid((N + 63) / 64, 4);
    int nwb = (N + 3) / 4;  // wave-per-node blocks

    // --- layer 0 ---
    k_gemm_dual<<<ggrid, 256, 0, stream>>>(x, c0W, XW, l0W, l0b, H0, N);
    k_alsald<<<(N * 4 + 255) / 256, 256, 0, stream>>>(XW, c0as, c0ad, ALS, ALD, N);
    k_agg4<<<nwb, 256, 0, stream>>>(rowptr, col, XW, ALS, ALD, c0b, H0, N);

    // --- layer 1 ---
    k_gemm_dual<<<ggrid, 256, 0, stream>>>(H0, c1W, XW, l1W, l1b, H1, N);
    k_alsald<<<(N * 4 + 255) / 256, 256, 0, stream>>>(XW, c1as, c1ad, ALS, ALD, N);
    k_agg4<<<nwb, 256, 0, stream>>>(rowptr, col, XW, ALS, ALD, c1b, H1, N);

    // --- layer 2 ---
    k_l2prep<<<nwb, 256, 0, stream>>>(H1, c2W, c2as, c2ad, l2W, l2b,
                                      XW, ALS, ALD, out, N);
    k_agg2<<<nwb, 256, 0, stream>>>(rowptr, col, XW, ALS, ALD, c2b, out, N);
}

// Round 2
// 538.348 us; speedup vs baseline: 1.5573x; 1.5573x over previous
//
#include <hip/hip_runtime.h>
#include <hip/hip_bf16.h>

// GAT: 3x (GATConv + Linear skip), N=50000, E=800000(+N self loops)
// IN=128, HID=32, H=4, H_LAST=6, OUT=2, NEG=0.2
// R2: bf16-MFMA GEMMs (no LDS, weights transposed+L1-resident),
//     single-pass softmax aggregation (no max sweep, fused sum), 4x unroll.

#define NEG_SLOPE 0.2f

typedef __attribute__((ext_vector_type(8))) short short8;
typedef __attribute__((ext_vector_type(4))) float floatx4;

static __device__ __forceinline__ float leaky(float x) {
    return x > 0.f ? x : NEG_SLOPE * x;
}

static __device__ __forceinline__ unsigned short f2bf(float f) {
    unsigned int u = __float_as_uint(f);
    u = (u + 0x7fffu + ((u >> 16) & 1u)) >> 16;  // RNE
    return (unsigned short)u;
}

// ---------------- CSR build ----------------

__global__ void k_hist(const int* ei, int E, int N, int* cnt) {
    int e = blockIdx.x * blockDim.x + threadIdx.x;
    if (e >= E + N) return;
    int d = (e < E) ? ei[E + e] : (e - E);
    atomicAdd(&cnt[d], 1);
}

__global__ void k_scan1(const int* cnt, int* incl, int* bsum, int N) {
    __shared__ int sm[256];
    int tid = threadIdx.x;
    int i = blockIdx.x * 256 + tid;
    int v = (i < N) ? cnt[i] : 0;
    sm[tid] = v;
    __syncthreads();
    for (int off = 1; off < 256; off <<= 1) {
        int t = (tid >= off) ? sm[tid - off] : 0;
        __syncthreads();
        sm[tid] += t;
        __syncthreads();
    }
    if (i < N) incl[i] = sm[tid];
    if (tid == 255) bsum[blockIdx.x] = sm[255];
}

__global__ void k_scan2(int* bsum, int nb) {
    __shared__ int sm[1024];
    int tid = threadIdx.x;
    int v = (tid < nb) ? bsum[tid] : 0;
    sm[tid] = v;
    __syncthreads();
    for (int off = 1; off < 1024; off <<= 1) {
        int t = (tid >= off) ? sm[tid - off] : 0;
        __syncthreads();
        sm[tid] += t;
        __syncthreads();
    }
    if (tid < nb) bsum[tid] = sm[tid] - v;  // exclusive block offsets
}

__global__ void k_scan3(int* rowptr, const int* cnt, const int* bsum, int N) {
    int i = blockIdx.x * 256 + threadIdx.x;
    if (i >= N) return;
    int incl = rowptr[i];
    int c = cnt[i];
    int excl = incl - c + bsum[blockIdx.x];
    rowptr[i] = excl;
    if (i == N - 1) rowptr[N] = excl + c;
}

__global__ void k_scatter(const int* ei, int E, int N, const int* rowptr, int* cnt, int* col) {
    int e = blockIdx.x * blockDim.x + threadIdx.x;
    if (e >= E + N) return;
    int s, d;
    if (e < E) { s = ei[e]; d = ei[E + e]; }
    else       { s = e - E; d = e - E; }
    int pos = rowptr[d] + atomicAdd(&cnt[d], 1);
    col[pos] = s;
}

// ---------------- converts ----------------

// x fp32 [N,128] -> Ab bf16 [Mpad,128], zero rows >= N
__global__ void k_conv_x(const float* __restrict__ x, unsigned short* __restrict__ Ab,
                         int N, int Mpad) {
    int t = blockIdx.x * 256 + threadIdx.x;       // one thread = 4 elems
    if (t >= Mpad * 32) return;
    int r = t >> 5;
    float4 v = make_float4(0.f, 0.f, 0.f, 0.f);
    if (r < N) v = ((const float4*)x)[t];
    ushort4 o;
    o.x = f2bf(v.x); o.y = f2bf(v.y); o.z = f2bf(v.z); o.w = f2bf(v.w);
    ((ushort4*)Ab)[t] = o;
}

// transpose+convert four 128x128 weights: WT[n][k] = bf16(W[k][n])
__global__ void k_conv_w(const float* W0, unsigned short* T0,
                         const float* W1, unsigned short* T1,
                         const float* W2, unsigned short* T2,
                         const float* W3, unsigned short* T3) {
    const float* W; unsigned short* T;
    switch (blockIdx.y) {
        case 0: W = W0; T = T0; break;
        case 1: W = W1; T = T1; break;
        case 2: W = W2; T = T2; break;
        default: W = W3; T = T3; break;
    }
    int t = blockIdx.x * 256 + threadIdx.x;  // 16384
    int n = t >> 7, k = t & 127;
    T[n * 128 + k] = f2bf(W[k * 128 + n]);
}

// ---------------- MFMA GEMM: C = Ab @ W^T(stored as WT[n][k]) -------------
// grid.y: 0 -> (W1T, C1, no bias), 1 -> (W2T, C2, +b2)
__global__ __launch_bounds__(256) void k_gemm_mfma(
    const unsigned short* __restrict__ Ab,   // [Mpad,128] bf16
    const unsigned short* __restrict__ W1T,  // [128,128] bf16, n-major
    float* __restrict__ C1,
    const unsigned short* __restrict__ W2T,
    const float* __restrict__ b2,
    float* __restrict__ C2,
    int M) {
    int which = blockIdx.y;
    const unsigned short* WT = which ? W2T : W1T;
    float* C = which ? C2 : C1;
    int row0 = blockIdx.x * 64;
    int w = threadIdx.x >> 6, lane = threadIdx.x & 63;
    int m = lane & 15, q = lane >> 4;

    const short8* A8 = (const short8*)Ab;
    const short8* W8 = (const short8*)WT;

    floatx4 acc[8];
#pragma unroll
    for (int ct = 0; ct < 8; ct++) acc[ct] = (floatx4){0.f, 0.f, 0.f, 0.f};

    int arow = row0 + w * 16 + m;
#pragma unroll
    for (int ks = 0; ks < 4; ks++) {
        short8 afrag = A8[arow * 16 + ks * 4 + q];
#pragma unroll
        for (int ct = 0; ct < 8; ct++) {
            short8 bfrag = W8[(ct * 16 + m) * 16 + ks * 4 + q];
            acc[ct] = __builtin_amdgcn_mfma_f32_16x16x32_bf16(afrag, bfrag, acc[ct], 0, 0, 0);
        }
    }

    int crow0 = row0 + w * 16 + q * 4;
#pragma unroll
    for (int ct = 0; ct < 8; ct++) {
        int gc = ct * 16 + m;
        float bias = which ? b2[gc] : 0.f;
#pragma unroll
        for (int r = 0; r < 4; r++) {
            int gr = crow0 + r;
            if (gr < M) C[gr * 128 + gc] = acc[ct][r] + bias;
        }
    }
}

// ---------------- attention logits per node/head (H=4, C=32) ----------------
__global__ void k_alsald(const float* __restrict__ XW,
                         const float* __restrict__ a_s, const float* __restrict__ a_d,
                         float* __restrict__ ALS, float* __restrict__ ALD, int N) {
    int t = blockIdx.x * blockDim.x + threadIdx.x;
    if (t >= N * 4) return;
    int n = t >> 2, h = t & 3;
    const float* xr = XW + n * 128 + h * 32;
    const float* as = a_s + h * 32;
    const float* ad = a_d + h * 32;
    float s = 0.f, d = 0.f;
#pragma unroll
    for (int c = 0; c < 32; c++) {
        float v = xr[c];
        s += v * as[c];
        d += v * ad[c];
    }
    ALS[n * 4 + h] = s;
    ALD[n * 4 + h] = d;
}

// -------- single-pass aggregation H=4,C=32 concat + skip + relu ------------
// H in/out (contains skip on entry). Hb (optional) gets bf16 copy of output.
__global__ __launch_bounds__(256) void k_agg4(
    const int* __restrict__ rowptr, const int* __restrict__ col,
    const float* __restrict__ XW, const float* __restrict__ ALS,
    const float* __restrict__ ALD, const float* __restrict__ cb,
    float* __restrict__ H, unsigned short* __restrict__ Hb, int N) {
    int wid = threadIdx.x >> 6, lane = threadIdx.x & 63;
    int node = blockIdx.x * 4 + wid;
    if (node >= N) return;
    int start = rowptr[node], end = rowptr[node + 1];

    int hi = (lane >> 5) & 1;
    int hA = hi, hB = hi + 2;
    float aldA = ALD[node * 4 + hA];
    float aldB = ALD[node * 4 + hB];

    float accA = 0.f, accB = 0.f, sA = 0.f, sB = 0.f;
    int i = start;
    for (; i + 4 <= end; i += 4) {
        int s0 = col[i], s1 = col[i + 1], s2 = col[i + 2], s3 = col[i + 3];
        float a0A = ALS[s0 * 4 + hA], a0B = ALS[s0 * 4 + hB];
        float a1A = ALS[s1 * 4 + hA], a1B = ALS[s1 * 4 + hB];
        float a2A = ALS[s2 * 4 + hA], a2B = ALS[s2 * 4 + hB];
        float a3A = ALS[s3 * 4 + hA], a3B = ALS[s3 * 4 + hB];
        float x0A = XW[s0 * 128 + lane], x0B = XW[s0 * 128 + 64 + lane];
        float x1A = XW[s1 * 128 + lane], x1B = XW[s1 * 128 + 64 + lane];
        float x2A = XW[s2 * 128 + lane], x2B = XW[s2 * 128 + 64 + lane];
        float x3A = XW[s3 * 128 + lane], x3B = XW[s3 * 128 + 64 + lane];
        float e0A = __expf(leaky(a0A + aldA)), e0B = __expf(leaky(a0B + aldB));
        float e1A = __expf(leaky(a1A + aldA)), e1B = __expf(leaky(a1B + aldB));
        float e2A = __expf(leaky(a2A + aldA)), e2B = __expf(leaky(a2B + aldB));
        float e3A = __expf(leaky(a3A + aldA)), e3B = __expf(leaky(a3B + aldB));
        sA += e0A + e1A + e2A + e3A;
        sB += e0B + e1B + e2B + e3B;
        accA += e0A * x0A + e1A * x1A + e2A * x2A + e3A * x3A;
        accB += e0B * x0B + e1B * x1B + e2B * x2B + e3B * x3B;
    }
    for (; i < end; i++) {
        int s = col[i];
        float eA = __expf(leaky(ALS[s * 4 + hA] + aldA));
        float eB = __expf(leaky(ALS[s * 4 + hB] + aldB));
        sA += eA; sB += eB;
        accA += eA * XW[s * 128 + lane];
        accB += eB * XW[s * 128 + 64 + lane];
    }

    int oc1 = lane, oc2 = lane + 64;
    float o1 = accA / sA + cb[oc1] + H[node * 128 + oc1];
    float o2 = accB / sB + cb[oc2] + H[node * 128 + oc2];
    o1 = o1 > 0.f ? o1 : 0.f;
    o2 = o2 > 0.f ? o2 : 0.f;
    H[node * 128 + oc1] = o1;
    H[node * 128 + oc2] = o2;
    if (Hb) {
        Hb[node * 128 + oc1] = f2bf(o1);
        Hb[node * 128 + oc2] = f2bf(o2);
    }
}

// ---------------- layer 2 prep: XW2[N,12], ALS2/ALD2[N,6], lin2 -> out ------
__global__ __launch_bounds__(256) void k_l2prep(
    const float* __restrict__ H1, const float* __restrict__ c2W,
    const float* __restrict__ c2as, const float* __restrict__ c2ad,
    const float* __restrict__ l2W, const float* __restrict__ l2b,
    float* __restrict__ XW2, float* __restrict__ ALS2, float* __restrict__ ALD2,
    float* __restrict__ out, int N) {
    int wid = threadIdx.x >> 6, lane = threadIdx.x & 63;
    int node = blockIdx.x * 4 + wid;
    if (node >= N) return;
    float h1 = H1[node * 128 + lane];
    float h2 = H1[node * 128 + 64 + lane];
    float p[14];
#pragma unroll
    for (int j = 0; j < 12; j++)
        p[j] = h1 * c2W[lane * 12 + j] + h2 * c2W[(lane + 64) * 12 + j];
    p[12] = h1 * l2W[lane * 2 + 0] + h2 * l2W[(lane + 64) * 2 + 0];
    p[13] = h1 * l2W[lane * 2 + 1] + h2 * l2W[(lane + 64) * 2 + 1];
#pragma unroll
    for (int m = 32; m >= 1; m >>= 1)
#pragma unroll
        for (int j = 0; j < 14; j++) p[j] += __shfl_xor(p[j], m);
    if (lane == 0) {
#pragma unroll
        for (int h = 0; h < 6; h++) {
            float a = p[h * 2] * c2as[h * 2] + p[h * 2 + 1] * c2as[h * 2 + 1];
            float d = p[h * 2] * c2ad[h * 2] + p[h * 2 + 1] * c2ad[h * 2 + 1];
            ALS2[node * 6 + h] = a;
            ALD2[node * 6 + h] = d;
        }
#pragma unroll
        for (int j = 0; j < 12; j++) XW2[node * 12 + j] = p[j];
        out[node * 2 + 0] = p[12] + l2b[0];
        out[node * 2 + 1] = p[13] + l2b[1];
    }
}

// ---------- single-pass aggregation H_LAST=6, C=2, mean, + c2_b ------------
__global__ __launch_bounds__(256) void k_agg2(
    const int* __restrict__ rowptr, const int* __restrict__ col,
    const float* __restrict__ XW2, const float* __restrict__ ALS2,
    const float* __restrict__ ALD2, const float* __restrict__ c2b,
    float* __restrict__ out, int N) {
    int wid = threadIdx.x >> 6, lane = threadIdx.x & 63;
    int node = blockIdx.x * 4 + wid;
    if (node >= N) return;
    int start = rowptr[node], end = rowptr[node + 1];

    float acc = 0.f, se = 0.f;
    int h = (lane < 12) ? (lane >> 1) : 0;
    float aldh = ALD2[node * 6 + h];
    if (lane < 12) {
        int i = start;
        for (; i + 2 <= end; i += 2) {
            int s0 = col[i], s1 = col[i + 1];
            float e0 = __expf(leaky(ALS2[s0 * 6 + h] + aldh));
            float e1 = __expf(leaky(ALS2[s1 * 6 + h] + aldh));
            float y0 = XW2[s0 * 12 + lane];
            float y1 = XW2[s1 * 12 + lane];
            se += e0 + e1;
            acc += e0 * y0 + e1 * y1;
        }
        for (; i < end; i++) {
            int s = col[i];
            float e = __expf(leaky(ALS2[s * 6 + h] + aldh));
            se += e;
            acc += e * XW2[s * 12 + lane];
        }
    }
    float v = (lane < 12) ? acc / se : 0.f;
    v += __shfl_xor(v, 2);
    v += __shfl_xor(v, 4);
    v += __shfl_xor(v, 8);
    if (lane < 2)
        out[node * 2 + lane] += v * (1.f / 6.f) + c2b[lane];
}

// ---------------- launch ----------------

extern "C" void kernel_launch(void* const* d_in, const int* in_sizes, int n_in,
                              void* d_out, int out_size, void* d_ws, size_t ws_size,
                              hipStream_t stream) {
    const float* x   = (const float*)d_in[0];
    const int* ei    = (const int*)d_in[1];
    // d_in[2] edge_attr: ignored
    const float* c0W = (const float*)d_in[3];
    const float* c0as = (const float*)d_in[4];
    const float* c0ad = (const float*)d_in[5];
    const float* c0b = (const float*)d_in[6];
    const float* l0W = (const float*)d_in[7];
    const float* l0b = (const float*)d_in[8];
    const float* c1W = (const float*)d_in[9];
    const float* c1as = (const float*)d_in[10];
    const float* c1ad = (const float*)d_in[11];
    const float* c1b = (const float*)d_in[12];
    const float* l1W = (const float*)d_in[13];
    const float* l1b = (const float*)d_in[14];
    const float* c2W = (const float*)d_in[15];
    const float* c2as = (const float*)d_in[16];
    const float* c2ad = (const float*)d_in[17];
    const float* c2b = (const float*)d_in[18];
    const float* l2W = (const float*)d_in[19];
    const float* l2b = (const float*)d_in[20];
    float* out = (float*)d_out;

    const int N = in_sizes[0] / 128;
    const int E = in_sizes[1] / 2;
    const int ET = E + N;
    const int Mpad = (N + 63) & ~63;

    // workspace carve (256B aligned)
    char* p = (char*)d_ws;
    auto alloc = [&](size_t bytes) -> void* {
        void* r = (void*)p;
        p += (bytes + 255) & ~(size_t)255;
        return r;
    };
    float* H   = (float*)alloc((size_t)N * 128 * 4);        // skip + layer output (reused L0/L1)
    float* XW  = (float*)alloc((size_t)N * 128 * 4);        // conv transform (reused as XW2)
    unsigned short* Ab = (unsigned short*)alloc((size_t)Mpad * 128 * 2);  // bf16 GEMM input
    unsigned short* W1T = (unsigned short*)alloc(128 * 128 * 2);
    unsigned short* W2T = (unsigned short*)alloc(128 * 128 * 2);
    unsigned short* W3T = (unsigned short*)alloc(128 * 128 * 2);
    unsigned short* W4T = (unsigned short*)alloc(128 * 128 * 2);
    float* ALS = (float*)alloc((size_t)N * 6 * 4);
    float* ALD = (float*)alloc((size_t)N * 6 * 4);
    int* rowptr = (int*)alloc((size_t)(N + 1) * 4);
    int* cnt    = (int*)alloc((size_t)N * 4);
    int* bsum   = (int*)alloc(4096);
    int* col    = (int*)alloc((size_t)ET * 4);

    const int nb = (N + 255) / 256;

    // --- CSR build ---
    hipMemsetAsync(cnt, 0, (size_t)N * 4, stream);
    k_hist<<<(ET + 255) / 256, 256, 0, stream>>>(ei, E, N, cnt);
    k_scan1<<<nb, 256, 0, stream>>>(cnt, rowptr, bsum, N);
    k_scan2<<<1, 1024, 0, stream>>>(bsum, nb);
    k_scan3<<<nb, 256, 0, stream>>>(rowptr, cnt, bsum, N);
    hipMemsetAsync(cnt, 0, (size_t)N * 4, stream);
    k_scatter<<<(ET + 255) / 256, 256, 0, stream>>>(ei, E, N, rowptr, cnt, col);

    // --- converts ---
    k_conv_x<<<(Mpad * 32 + 255) / 256, 256, 0, stream>>>(x, Ab, N, Mpad);
    dim3 wgrid(64, 4);
    k_conv_w<<<wgrid, 256, 0, stream>>>(c0W, W1T, l0W, W2T, c1W, W3T, l1W, W4T);

    dim3 ggrid(Mpad / 64, 2);
    int nwb = (N + 3) / 4;  // wave-per-node blocks

    // --- layer 0 ---
    k_gemm_mfma<<<ggrid, 256, 0, stream>>>(Ab, W1T, XW, W2T, l0b, H, N);
    k_alsald<<<(N * 4 + 255) / 256, 256, 0, stream>>>(XW, c0as, c0ad, ALS, ALD, N);
    k_agg4<<<nwb, 256, 0, stream>>>(rowptr, col, XW, ALS, ALD, c0b, H, Ab, N);

    // --- layer 1 --- (Ab now holds bf16(H0); pad rows still zero from k_conv_x)
    k_gemm_mfma<<<ggrid, 256, 0, stream>>>(Ab, W3T, XW, W4T, l1b, H, N);
    k_alsald<<<(N * 4 + 255) / 256, 256, 0, stream>>>(XW, c1as, c1ad, ALS, ALD, N);
    k_agg4<<<nwb, 256, 0, stream>>>(rowptr, col, XW, ALS, ALD, c1b, H, nullptr, N);

    // --- layer 2 ---
    k_l2prep<<<nwb, 256, 0, stream>>>(H, c2W, c2as, c2ad, l2W, l2b,
                                      XW, ALS, ALD, out, N);
    k_agg2<<<nwb, 256, 0, stream>>>(rowptr, col, XW, ALS, ALD, c2b, out, N);
}